// Round 1
// baseline (1139.934 us; speedup 1.0000x reference)
//
#include <hip/hip_runtime.h>
#include <math.h>

#define NB 8
#define NT 800
#define NC 8
#define NF 513
#define NFT 9      // ceil(513/64) f-tiles of 64 lanes
#define NTC 16     // t chunks
#define TCHUNK 50  // 16*50 = 800
#define NE 146     // 72 (psd_s tri) + 72 (psd_n tri) + S_s + S_n
#define NPAIR 36

// Partial slot layout: part[(((tc*NB+b)*NFT+ft)*NE + entry)*64 + lane]
// entry 2p/2p+1   : psd_s pair p (c<=e), re/im, p = c*8 - c(c+1)/2 + e
// entry 72+2p/...+1: psd_n pair p
// entry 144/145   : S_s / S_n (sum over t-chunk of mean_c clamped mask)

__device__ __forceinline__ void accum_psd(const float* __restrict__ drb,
                                          const float* __restrict__ dib, int t,
                                          float m_s, float m_n,
                                          float* __restrict__ sr, float* __restrict__ si,
                                          float* __restrict__ nr, float* __restrict__ ni) {
  float xr[NC], xi[NC];
#pragma unroll
  for (int c = 0; c < NC; c++) {
    xr[c] = drb[(t * NC + c) * NF];
    xi[c] = dib[(t * NC + c) * NF];
  }
  int p = 0;
#pragma unroll
  for (int c = 0; c < NC; c++) {
#pragma unroll
    for (int e = c; e < NC; e++) {
      // psd[c][e] += m * x[c]*conj(x[e])
      float pr = xr[c] * xr[e] + xi[c] * xi[e];
      float pi = xi[c] * xr[e] - xr[c] * xi[e];
      sr[p] += m_s * pr; si[p] += m_s * pi;
      nr[p] += m_n * pr; ni[p] += m_n * pi;
      p++;
    }
  }
}

__global__ __launch_bounds__(64, 2)
void k_psd_partial(const float* __restrict__ dr, const float* __restrict__ di,
                   const float* __restrict__ ms, const float* __restrict__ mn,
                   float* __restrict__ part) {
  const int fl = threadIdx.x;
  const int ft = blockIdx.x, b = blockIdx.y, tc = blockIdx.z;
  const int f = ft * 64 + fl;

  float sr[NPAIR], si[NPAIR], nr[NPAIR], ni[NPAIR];
#pragma unroll
  for (int p = 0; p < NPAIR; p++) { sr[p] = 0.f; si[p] = 0.f; nr[p] = 0.f; ni[p] = 0.f; }
  float Ss = 0.f, Sn = 0.f;

  if (f < NF) {
    const float* drb = dr + (size_t)b * NT * NC * NF + f;
    const float* dib = di + (size_t)b * NT * NC * NF + f;
    const float* msb = ms + ((size_t)b * NF + f) * NC * NT;
    const float* mnb = mn + ((size_t)b * NF + f) * NC * NT;
    const int t0 = tc * TCHUNK;
    for (int tb = 0; tb < TCHUNK; tb += 2) {
      const int t = t0 + tb;
      float ms0 = 0.f, ms1 = 0.f, mn0 = 0.f, mn1 = 0.f;
#pragma unroll
      for (int c = 0; c < NC; c++) {
        float2 a = *(const float2*)(msb + c * NT + t);
        float2 bq = *(const float2*)(mnb + c * NT + t);
        ms0 += fmaxf(a.x, 1e-6f);  ms1 += fmaxf(a.y, 1e-6f);
        mn0 += fmaxf(bq.x, 1e-6f); mn1 += fmaxf(bq.y, 1e-6f);
      }
      ms0 *= 0.125f; ms1 *= 0.125f; mn0 *= 0.125f; mn1 *= 0.125f;
      Ss += ms0 + ms1; Sn += mn0 + mn1;
      accum_psd(drb, dib, t,     ms0, mn0, sr, si, nr, ni);
      accum_psd(drb, dib, t + 1, ms1, mn1, sr, si, nr, ni);
    }
  }

  float* out = part + (((size_t)(tc * NB + b) * NFT + ft) * NE) * 64 + fl;
#pragma unroll
  for (int p = 0; p < NPAIR; p++) { out[(2 * p) * 64] = sr[p]; out[(2 * p + 1) * 64] = si[p]; }
#pragma unroll
  for (int p = 0; p < NPAIR; p++) { out[(72 + 2 * p) * 64] = nr[p]; out[(72 + 2 * p + 1) * 64] = ni[p]; }
  out[144 * 64] = Ss;
  out[145 * 64] = Sn;
}

// One block per (b,c): build feat row (LDS), then 320 threads = A do the MLP dot.
__global__ __launch_bounds__(320)
void k_attention(const float* __restrict__ part,
                 const float* __restrict__ mlp_w, const float* __restrict__ mlp_b,
                 const float* __restrict__ gvec_w, const float* __restrict__ gvec_b,
                 float* __restrict__ e_buf) {
  __shared__ float feat[NF];
  __shared__ float wred[5];
  const int b = blockIdx.x >> 3, c = blockIdx.x & 7;
  const int tid = threadIdx.x;

  for (int f = tid; f < NF; f += 320) {
    const int ft = f >> 6, fl = f & 63;
    float rs = 0.f, is = 0.f, S = 0.f;
    for (int tc = 0; tc < NTC; ++tc) {
      const float* base = part + (((size_t)(tc * NB + b) * NFT + ft) * NE) * 64 + fl;
#pragma unroll
      for (int e = 0; e < NC; ++e) {
        if (e == c) continue;
        const int lo = (e < c) ? e : c, hi = (e < c) ? c : e;
        const int p = lo * 8 - (lo * (lo + 1)) / 2 + hi;
        rs += base[(2 * p) * 64];
        const float im = base[(2 * p + 1) * 64];
        is += (e > c) ? im : -im;   // row c: e<c needs conj
      }
      S += base[144 * 64];
    }
    feat[f] = sqrtf(rs * rs + is * is) / (7.f * (S + 1e-15f));
  }
  __syncthreads();

  const int a = tid;  // blockDim == 320 == A
  float acc = mlp_b[a];
  for (int f = 0; f < NF; ++f) acc = fmaf(feat[f], mlp_w[f * 320 + a], acc);
  float contrib = tanhf(acc) * gvec_w[a];
#pragma unroll
  for (int off = 32; off > 0; off >>= 1) contrib += __shfl_down(contrib, off);
  if ((tid & 63) == 0) wred[tid >> 6] = contrib;
  __syncthreads();
  if (tid == 0) {
    float s = gvec_b[0];
#pragma unroll
    for (int w = 0; w < 5; ++w) s += wred[w];
    e_buf[blockIdx.x] = s;
  }
}

__global__ void k_softmax_u(const float* __restrict__ e_buf, float* __restrict__ u_buf) {
  const int b = threadIdx.x;
  if (b < NB) {
    float v[NC], m = -1e30f;
#pragma unroll
    for (int c = 0; c < NC; c++) { v[c] = 2.f * e_buf[b * 8 + c]; m = fmaxf(m, v[c]); }
    float s = 0.f;
#pragma unroll
    for (int c = 0; c < NC; c++) { v[c] = expf(v[c] - m); s += v[c]; }
    const float inv = 1.f / s;
#pragma unroll
    for (int c = 0; c < NC; c++) u_buf[b * 8 + c] = v[c] * inv;
  }
}

// Thread per (b,f): reduce slots, complex Cholesky of psd_n, solve 8 RHS columns
// of psd_s, trace-normalize, contract with u -> ws[b,f,:].
__global__ __launch_bounds__(64, 1)
void k_solve(const float* __restrict__ part, const float* __restrict__ u_buf,
             float* __restrict__ wsvec) {
  const int fl = threadIdx.x, ft = blockIdx.x, b = blockIdx.y;
  const int f = ft * 64 + fl;
  if (f >= NF) return;
  const float* base = part + (((size_t)b * NFT + ft) * NE) * 64 + fl;
  const size_t tcstride = (size_t)NB * NFT * NE * 64;

  // A = psd_n, lower triangle (A[i][j], i>=j). entry p(j,i) holds psd_n[j][i] (j<=i):
  // psd_n[i][j] = conj(entry) for i>j.
  float Ar[8][8], Ai[8][8];
#pragma unroll
  for (int j = 0; j < 8; j++) {
#pragma unroll
    for (int i = j; i < 8; i++) {
      const int p = j * 8 - (j * (j + 1)) / 2 + i;
      float re = 0.f, im = 0.f;
      for (int tc = 0; tc < NTC; tc++) {
        const float* q = base + tc * tcstride;
        re += q[(72 + 2 * p) * 64];
        im += q[(72 + 2 * p + 1) * 64];
      }
      Ar[i][j] = re;
      Ai[i][j] = (i == j) ? 0.f : -im;
    }
  }
#pragma unroll
  for (int i = 0; i < 8; i++) Ar[i][i] += 1e-15f;

  // In-place complex Cholesky (lower). Diag kept via dinv.
  float dinv[8];
#pragma unroll
  for (int k = 0; k < 8; k++) {
    const float d = sqrtf(fmaxf(Ar[k][k], 1e-30f));
    const float id = 1.f / d;
    dinv[k] = id;
#pragma unroll
    for (int i = k + 1; i < 8; i++) { Ar[i][k] *= id; Ai[i][k] *= id; }
#pragma unroll
    for (int j = k + 1; j < 8; j++) {
#pragma unroll
      for (int i = j; i < 8; i++) {
        Ar[i][j] -= Ar[i][k] * Ar[j][k] + Ai[i][k] * Ai[j][k];
        Ai[i][j] -= Ai[i][k] * Ar[j][k] - Ar[i][k] * Ai[j][k];
      }
    }
  }

  float trr = 0.f, tri = 0.f;
  float war[8], wai[8];
#pragma unroll
  for (int e = 0; e < 8; e++) { war[e] = 0.f; wai[e] = 0.f; }
  const float* ub = u_buf + b * 8;

#pragma unroll
  for (int c = 0; c < 8; c++) {
    // column c of psd_s: s[e] = psd_s[e][c]
    float syr[8], syi[8];
#pragma unroll
    for (int e = 0; e < 8; e++) {
      const int lo = (e < c) ? e : c, hi = (e < c) ? c : e;
      const int p = lo * 8 - (lo * (lo + 1)) / 2 + hi;
      float re = 0.f, im = 0.f;
      for (int tc = 0; tc < NTC; tc++) {
        const float* q = base + tc * tcstride;
        re += q[(2 * p) * 64];
        im += q[(2 * p + 1) * 64];
      }
      syr[e] = re;
      syi[e] = (e <= c) ? im : -im;  // e>c: conj(psd_s[c][e])
    }
    // forward: L y = s
    float yr[8], yi[8];
#pragma unroll
    for (int i = 0; i < 8; i++) {
      float ar = syr[i], ai = syi[i];
#pragma unroll
      for (int m = 0; m < 8; m++) {
        if (m < i) {
          ar -= Ar[i][m] * yr[m] - Ai[i][m] * yi[m];
          ai -= Ar[i][m] * yi[m] + Ai[i][m] * yr[m];
        }
      }
      yr[i] = ar * dinv[i]; yi[i] = ai * dinv[i];
    }
    // backward: L^H z = y
    float zr[8], zi[8];
#pragma unroll
    for (int i = 7; i >= 0; i--) {
      float ar = yr[i], ai = yi[i];
#pragma unroll
      for (int m = 0; m < 8; m++) {
        if (m > i) {
          ar -= Ar[m][i] * zr[m] + Ai[m][i] * zi[m];
          ai -= Ar[m][i] * zi[m] - Ai[m][i] * zr[m];
        }
      }
      zr[i] = ar * dinv[i]; zi[i] = ai * dinv[i];
    }
    trr += zr[c]; tri += zi[c];
    const float uc = ub[c];
#pragma unroll
    for (int e = 0; e < 8; e++) { war[e] += zr[e] * uc; wai[e] += zi[e] * uc; }
  }

  const float denr = trr + 1e-15f, deni = tri;
  const float inv = 1.f / (denr * denr + deni * deni);
  float2* wv = (float2*)wsvec + ((size_t)b * NF + f) * 8;
#pragma unroll
  for (int e = 0; e < 8; e++) {
    wv[e] = make_float2((war[e] * denr + wai[e] * deni) * inv,
                        (wai[e] * denr - war[e] * deni) * inv);
  }
}

__global__ __launch_bounds__(256)
void k_apply(const float* __restrict__ dr, const float* __restrict__ di,
             const float* __restrict__ wsvec, float* __restrict__ out) {
  const int ftile = blockIdx.x, b = blockIdx.y, tt = blockIdx.z;
  const int f = ftile * 256 + threadIdx.x;
  if (f >= NF) return;
  float wr[8], wi[8];
  const float2* wv = (const float2*)wsvec + ((size_t)b * NF + f) * 8;
#pragma unroll
  for (int c = 0; c < 8; c++) { float2 w = wv[c]; wr[c] = w.x; wi[c] = w.y; }
  const float* drb = dr + (size_t)b * NT * NC * NF + f;
  const float* dib = di + (size_t)b * NT * NC * NF + f;
  float2* ob = (float2*)out + (size_t)b * NT * NF + f;
  const int t1 = tt * 32 + 32;
  for (int t = tt * 32; t < t1; ++t) {
    float re = 0.f, im = 0.f;
#pragma unroll
    for (int c = 0; c < 8; c++) {
      const float xr = drb[(t * NC + c) * NF];
      const float xi = dib[(t * NC + c) * NF];
      // conj(ws) * x
      re += wr[c] * xr + wi[c] * xi;
      im += wr[c] * xi - wi[c] * xr;
    }
    ob[(size_t)t * NF] = make_float2(re, im);
  }
}

extern "C" void kernel_launch(void* const* d_in, const int* in_sizes, int n_in,
                              void* d_out, int out_size, void* d_ws, size_t ws_size,
                              hipStream_t stream) {
  const float* dr     = (const float*)d_in[0];
  const float* di     = (const float*)d_in[1];
  const float* msk_s  = (const float*)d_in[2];
  const float* msk_n  = (const float*)d_in[3];
  const float* mlp_w  = (const float*)d_in[4];
  const float* mlp_b  = (const float*)d_in[5];
  const float* gvec_w = (const float*)d_in[6];
  const float* gvec_b = (const float*)d_in[7];

  float* part  = (float*)d_ws;                                   // 10,764,288 floats
  float* e_buf = part + (size_t)NTC * NB * NFT * NE * 64;        // 64
  float* u_buf = e_buf + 64;                                     // 64
  float* wsvec = u_buf + 64;                                     // 65,664
  float* out   = (float*)d_out;

  k_psd_partial<<<dim3(NFT, NB, NTC), 64, 0, stream>>>(dr, di, msk_s, msk_n, part);
  k_attention<<<64, 320, 0, stream>>>(part, mlp_w, mlp_b, gvec_w, gvec_b, e_buf);
  k_softmax_u<<<1, 64, 0, stream>>>(e_buf, u_buf);
  k_solve<<<dim3(NFT, NB), 64, 0, stream>>>(part, u_buf, wsvec);
  k_apply<<<dim3(3, NB, 25), 256, 0, stream>>>(dr, di, wsvec, out);
}

// Round 2
// 538.791 us; speedup vs baseline: 2.1157x; 2.1157x over previous
//
#include <hip/hip_runtime.h>
#include <math.h>

#define NB 8
#define NT 800
#define NC 8
#define NF 513
#define NFT 9      // ceil(513/64) f-tiles of 64 lanes
#define NTC 16     // t chunks
#define TCHUNK 50  // 16*50 = 800
#define NE 146     // 72 (psd_s tri) + 72 (psd_n tri) + S_s + S_n
#define NPAIR 36

// Partial slot layout: part[(((tc*NB+b)*NFT+ft)*NE + entry)*64 + lane]
// Compact layout:      comp[((b*NFT+ft)*NE + entry)*64 + lane]
// entry 2p/2p+1    : psd_s pair p (c<=e), re/im, p = c*8 - c(c+1)/2 + e
// entry 72+2p/...+1: psd_n pair p
// entry 144/145    : S_s / S_n

// ---------------------------------------------------------------------------
// Phase A: mask reduce over c + transpose -> mred[b][t][f] (coalesced along f)
__global__ __launch_bounds__(256)
void k_maskred(const float* __restrict__ ms, const float* __restrict__ mn,
               float* __restrict__ mrs, float* __restrict__ mrn) {
  __shared__ float ts[64][65];   // +1 pad: transpose read is 2-way aliased (free)
  __shared__ float tn[64][65];
  const int tx = threadIdx.x & 63;
  const int wy = threadIdx.x >> 6;
  const int ft = blockIdx.x, tt = blockIdx.y, b = blockIdx.z;
  const int f0 = ft * 64, t0 = tt * 64;
  const int t = t0 + tx;
  const bool tvalid = (t < NT);

  for (int fl = wy; fl < 64; fl += 4) {
    const int f = f0 + fl;
    float as = 0.f, an = 0.f;
    if (f < NF && tvalid) {
      const float* mbs = ms + (((size_t)b * NF + f) * NC) * NT + t;
      const float* mbn = mn + (((size_t)b * NF + f) * NC) * NT + t;
#pragma unroll
      for (int c = 0; c < NC; c++) {
        as += fmaxf(mbs[c * NT], 1e-6f);
        an += fmaxf(mbn[c * NT], 1e-6f);
      }
    }
    ts[fl][tx] = as * 0.125f;
    tn[fl][tx] = an * 0.125f;
  }
  __syncthreads();
  for (int tl = wy; tl < 64; tl += 4) {
    const int tg = t0 + tl, f = f0 + tx;
    if (tg < NT && f < NF) {
      mrs[((size_t)b * NT + tg) * NF + f] = ts[tx][tl];
      mrn[((size_t)b * NT + tg) * NF + f] = tn[tx][tl];
    }
  }
}

// ---------------------------------------------------------------------------
__device__ __forceinline__ void accum_psd(const float* __restrict__ drb,
                                          const float* __restrict__ dib, int t,
                                          float m_s, float m_n,
                                          float* __restrict__ sr, float* __restrict__ si,
                                          float* __restrict__ nr, float* __restrict__ ni) {
  float xr[NC], xi[NC];
#pragma unroll
  for (int c = 0; c < NC; c++) {
    xr[c] = drb[(t * NC + c) * NF];
    xi[c] = dib[(t * NC + c) * NF];
  }
  int p = 0;
#pragma unroll
  for (int c = 0; c < NC; c++) {
#pragma unroll
    for (int e = c; e < NC; e++) {
      float pr = xr[c] * xr[e] + xi[c] * xi[e];
      float pi = xi[c] * xr[e] - xr[c] * xi[e];
      sr[p] += m_s * pr; si[p] += m_s * pi;
      nr[p] += m_n * pr; ni[p] += m_n * pi;
      p++;
    }
  }
}

__global__ __launch_bounds__(64, 2)
void k_psd_partial(const float* __restrict__ dr, const float* __restrict__ di,
                   const float* __restrict__ mrs, const float* __restrict__ mrn,
                   float* __restrict__ part) {
  const int fl = threadIdx.x;
  const int ft = blockIdx.x, b = blockIdx.y, tc = blockIdx.z;
  const int f = ft * 64 + fl;

  float sr[NPAIR], si[NPAIR], nr[NPAIR], ni[NPAIR];
#pragma unroll
  for (int p = 0; p < NPAIR; p++) { sr[p] = 0.f; si[p] = 0.f; nr[p] = 0.f; ni[p] = 0.f; }
  float Ss = 0.f, Sn = 0.f;

  if (f < NF) {
    const float* drb  = dr  + (size_t)b * NT * NC * NF + f;
    const float* dib  = di  + (size_t)b * NT * NC * NF + f;
    const float* mrsb = mrs + (size_t)b * NT * NF + f;
    const float* mrnb = mrn + (size_t)b * NT * NF + f;
    const int t0 = tc * TCHUNK;
    for (int tb = 0; tb < TCHUNK; tb += 2) {
      const int t = t0 + tb;
      const float ms0 = mrsb[(size_t)t * NF];
      const float ms1 = mrsb[(size_t)(t + 1) * NF];
      const float mn0 = mrnb[(size_t)t * NF];
      const float mn1 = mrnb[(size_t)(t + 1) * NF];
      Ss += ms0 + ms1; Sn += mn0 + mn1;
      accum_psd(drb, dib, t,     ms0, mn0, sr, si, nr, ni);
      accum_psd(drb, dib, t + 1, ms1, mn1, sr, si, nr, ni);
    }
  }

  float* out = part + (((size_t)(tc * NB + b) * NFT + ft) * NE) * 64 + fl;
#pragma unroll
  for (int p = 0; p < NPAIR; p++) { out[(2 * p) * 64] = sr[p]; out[(2 * p + 1) * 64] = si[p]; }
#pragma unroll
  for (int p = 0; p < NPAIR; p++) { out[(72 + 2 * p) * 64] = nr[p]; out[(72 + 2 * p + 1) * 64] = ni[p]; }
  out[144 * 64] = Ss;
  out[145 * 64] = Sn;
}

// ---------------------------------------------------------------------------
// Sum partials over tc -> compact psd buffer (tc is the outermost slot axis,
// so per-tc addresses are idx + tc*stride; reads/writes fully coalesced).
__global__ __launch_bounds__(256)
void k_reduce_parts(const float* __restrict__ part, float* __restrict__ comp) {
  const size_t total = (size_t)NB * NFT * NE * 64;
  const size_t idx = (size_t)blockIdx.x * 256 + threadIdx.x;
  if (idx >= total) return;
  const size_t stride = total;  // NB*NFT*NE*64 happens to equal per-tc stride
  float s = 0.f;
#pragma unroll
  for (int tc = 0; tc < NTC; tc++) s += part[(size_t)tc * stride + idx];
  comp[idx] = s;
}

// ---------------------------------------------------------------------------
__global__ __launch_bounds__(320)
void k_attention(const float* __restrict__ comp,
                 const float* __restrict__ mlp_w, const float* __restrict__ mlp_b,
                 const float* __restrict__ gvec_w, const float* __restrict__ gvec_b,
                 float* __restrict__ e_buf) {
  __shared__ float feat[NF];
  __shared__ float wred[5];
  const int b = blockIdx.x >> 3, c = blockIdx.x & 7;
  const int tid = threadIdx.x;

  for (int f = tid; f < NF; f += 320) {
    const int ft = f >> 6, fl = f & 63;
    const float* base = comp + (((size_t)b * NFT + ft) * NE) * 64 + fl;
    float rs = 0.f, is = 0.f;
#pragma unroll
    for (int e = 0; e < NC; ++e) {
      if (e == c) continue;
      const int lo = (e < c) ? e : c, hi = (e < c) ? c : e;
      const int p = lo * 8 - (lo * (lo + 1)) / 2 + hi;
      rs += base[(2 * p) * 64];
      const float im = base[(2 * p + 1) * 64];
      is += (e > c) ? im : -im;   // row c: e<c needs conj
    }
    const float S = base[144 * 64];
    feat[f] = sqrtf(rs * rs + is * is) / (7.f * (S + 1e-15f));
  }
  __syncthreads();

  const int a = tid;  // blockDim == 320 == A
  float acc = mlp_b[a];
  for (int f = 0; f < NF; ++f) acc = fmaf(feat[f], mlp_w[f * 320 + a], acc);
  float contrib = tanhf(acc) * gvec_w[a];
#pragma unroll
  for (int off = 32; off > 0; off >>= 1) contrib += __shfl_down(contrib, off);
  if ((tid & 63) == 0) wred[tid >> 6] = contrib;
  __syncthreads();
  if (tid == 0) {
    float s = gvec_b[0];
#pragma unroll
    for (int w = 0; w < 5; ++w) s += wred[w];
    e_buf[blockIdx.x] = s;
  }
}

__global__ void k_softmax_u(const float* __restrict__ e_buf, float* __restrict__ u_buf) {
  const int b = threadIdx.x;
  if (b < NB) {
    float v[NC], m = -1e30f;
#pragma unroll
    for (int c = 0; c < NC; c++) { v[c] = 2.f * e_buf[b * 8 + c]; m = fmaxf(m, v[c]); }
    float s = 0.f;
#pragma unroll
    for (int c = 0; c < NC; c++) { v[c] = expf(v[c] - m); s += v[c]; }
    const float inv = 1.f / s;
#pragma unroll
    for (int c = 0; c < NC; c++) u_buf[b * 8 + c] = v[c] * inv;
  }
}

// ---------------------------------------------------------------------------
// Thread per (b,f): complex Cholesky of psd_n, solve 8 RHS columns of psd_s,
// trace-normalize, contract with u -> ws[b,f,:].
__global__ __launch_bounds__(64, 1)
void k_solve(const float* __restrict__ comp, const float* __restrict__ u_buf,
             float* __restrict__ wsvec) {
  const int fl = threadIdx.x, ft = blockIdx.x, b = blockIdx.y;
  const int f = ft * 64 + fl;
  if (f >= NF) return;
  const float* base = comp + (((size_t)b * NFT + ft) * NE) * 64 + fl;

  float Ar[8][8], Ai[8][8];
#pragma unroll
  for (int j = 0; j < 8; j++) {
#pragma unroll
    for (int i = j; i < 8; i++) {
      const int p = j * 8 - (j * (j + 1)) / 2 + i;
      Ar[i][j] = base[(72 + 2 * p) * 64];
      Ai[i][j] = (i == j) ? 0.f : -base[(72 + 2 * p + 1) * 64];
    }
  }
#pragma unroll
  for (int i = 0; i < 8; i++) Ar[i][i] += 1e-15f;

  float dinv[8];
#pragma unroll
  for (int k = 0; k < 8; k++) {
    const float d = sqrtf(fmaxf(Ar[k][k], 1e-30f));
    const float id = 1.f / d;
    dinv[k] = id;
#pragma unroll
    for (int i = k + 1; i < 8; i++) { Ar[i][k] *= id; Ai[i][k] *= id; }
#pragma unroll
    for (int j = k + 1; j < 8; j++) {
#pragma unroll
      for (int i = j; i < 8; i++) {
        Ar[i][j] -= Ar[i][k] * Ar[j][k] + Ai[i][k] * Ai[j][k];
        Ai[i][j] -= Ai[i][k] * Ar[j][k] - Ar[i][k] * Ai[j][k];
      }
    }
  }

  float trr = 0.f, tri = 0.f;
  float war[8], wai[8];
#pragma unroll
  for (int e = 0; e < 8; e++) { war[e] = 0.f; wai[e] = 0.f; }
  const float* ub = u_buf + b * 8;

#pragma unroll
  for (int c = 0; c < 8; c++) {
    float syr[8], syi[8];
#pragma unroll
    for (int e = 0; e < 8; e++) {
      const int lo = (e < c) ? e : c, hi = (e < c) ? c : e;
      const int p = lo * 8 - (lo * (lo + 1)) / 2 + hi;
      syr[e] = base[(2 * p) * 64];
      const float im = base[(2 * p + 1) * 64];
      syi[e] = (e <= c) ? im : -im;
    }
    float yr[8], yi[8];
#pragma unroll
    for (int i = 0; i < 8; i++) {
      float ar = syr[i], ai = syi[i];
#pragma unroll
      for (int m = 0; m < 8; m++) {
        if (m < i) {
          ar -= Ar[i][m] * yr[m] - Ai[i][m] * yi[m];
          ai -= Ar[i][m] * yi[m] + Ai[i][m] * yr[m];
        }
      }
      yr[i] = ar * dinv[i]; yi[i] = ai * dinv[i];
    }
    float zr[8], zi[8];
#pragma unroll
    for (int i = 7; i >= 0; i--) {
      float ar = yr[i], ai = yi[i];
#pragma unroll
      for (int m = 0; m < 8; m++) {
        if (m > i) {
          ar -= Ar[m][i] * zr[m] + Ai[m][i] * zi[m];
          ai -= Ar[m][i] * zi[m] - Ai[m][i] * zr[m];
        }
      }
      zr[i] = ar * dinv[i]; zi[i] = ai * dinv[i];
    }
    trr += zr[c]; tri += zi[c];
    const float uc = ub[c];
#pragma unroll
    for (int e = 0; e < 8; e++) { war[e] += zr[e] * uc; wai[e] += zi[e] * uc; }
  }

  const float denr = trr + 1e-15f, deni = tri;
  const float inv = 1.f / (denr * denr + deni * deni);
  float2* wv = (float2*)wsvec + ((size_t)b * NF + f) * 8;
#pragma unroll
  for (int e = 0; e < 8; e++) {
    wv[e] = make_float2((war[e] * denr + wai[e] * deni) * inv,
                        (wai[e] * denr - war[e] * deni) * inv);
  }
}

// ---------------------------------------------------------------------------
__global__ __launch_bounds__(64)
void k_apply(const float* __restrict__ dr, const float* __restrict__ di,
             const float* __restrict__ wsvec, float* __restrict__ out) {
  const int ft = blockIdx.x, b = blockIdx.y, tt = blockIdx.z;
  const int f = ft * 64 + threadIdx.x;
  if (f >= NF) return;
  float wr[8], wi[8];
  const float2* wv = (const float2*)wsvec + ((size_t)b * NF + f) * 8;
#pragma unroll
  for (int c = 0; c < 8; c++) { float2 w = wv[c]; wr[c] = w.x; wi[c] = w.y; }
  const float* drb = dr + (size_t)b * NT * NC * NF + f;
  const float* dib = di + (size_t)b * NT * NC * NF + f;
  float2* ob = (float2*)out + (size_t)b * NT * NF + f;
  const int t1 = tt * 32 + 32;
  for (int t = tt * 32; t < t1; ++t) {
    float re = 0.f, im = 0.f;
#pragma unroll
    for (int c = 0; c < 8; c++) {
      const float xr = drb[(t * NC + c) * NF];
      const float xi = dib[(t * NC + c) * NF];
      re += wr[c] * xr + wi[c] * xi;   // conj(ws) * x
      im += wr[c] * xi - wi[c] * xr;
    }
    ob[(size_t)t * NF] = make_float2(re, im);
  }
}

extern "C" void kernel_launch(void* const* d_in, const int* in_sizes, int n_in,
                              void* d_out, int out_size, void* d_ws, size_t ws_size,
                              hipStream_t stream) {
  const float* dr     = (const float*)d_in[0];
  const float* di     = (const float*)d_in[1];
  const float* msk_s  = (const float*)d_in[2];
  const float* msk_n  = (const float*)d_in[3];
  const float* mlp_w  = (const float*)d_in[4];
  const float* mlp_b  = (const float*)d_in[5];
  const float* gvec_w = (const float*)d_in[6];
  const float* gvec_b = (const float*)d_in[7];

  float* part  = (float*)d_ws;                                   // 10,764,288 floats
  float* mrs   = part + (size_t)NTC * NB * NFT * NE * 64;        // 3,283,200
  float* mrn   = mrs + (size_t)NB * NT * NF;                     // 3,283,200
  float* comp  = mrn + (size_t)NB * NT * NF;                     // 672,768
  float* e_buf = comp + (size_t)NB * NFT * NE * 64;              // 64
  float* u_buf = e_buf + 64;                                     // 64
  float* wsvec = u_buf + 64;                                     // 65,664
  float* out   = (float*)d_out;

  k_maskred<<<dim3(NFT, 13, NB), 256, 0, stream>>>(msk_s, msk_n, mrs, mrn);
  k_psd_partial<<<dim3(NFT, NB, NTC), 64, 0, stream>>>(dr, di, mrs, mrn, part);
  {
    const size_t total = (size_t)NB * NFT * NE * 64;
    k_reduce_parts<<<(int)((total + 255) / 256), 256, 0, stream>>>(part, comp);
  }
  k_attention<<<64, 320, 0, stream>>>(comp, mlp_w, mlp_b, gvec_w, gvec_b, e_buf);
  k_softmax_u<<<1, 64, 0, stream>>>(e_buf, u_buf);
  k_solve<<<dim3(NFT, NB), 64, 0, stream>>>(comp, u_buf, wsvec);
  k_apply<<<dim3(NFT, NB, 25), 64, 0, stream>>>(dr, di, wsvec, out);
}

// Round 3
// 522.618 us; speedup vs baseline: 2.1812x; 1.0309x over previous
//
#include <hip/hip_runtime.h>
#include <math.h>

#define NB 8
#define NT 800
#define NC 8
#define NF 513
#define NFT 9      // ceil(513/64) f-tiles of 64 lanes
#define NTC 25     // t chunks
#define TCHUNK 32  // 25*32 = 800
#define NE 146     // 72 (psd_s tri) + 72 (psd_n tri) + S_s + S_n
#define NPAIR 36

// Compact layout: comp[((b*NFT+ft)*NE + entry)*64 + fl]
// entry 2p/2p+1    : psd_s pair p (c<=e), re/im, p = c*8 - c(c+1)/2 + e
// entry 72+2p/...+1: psd_n pair p
// entry 144/145    : S_s / S_n (atomically accumulated over t-chunks)

// ---------------------------------------------------------------------------
// Mask reduce over c + transpose -> mred[b][t][f], float4 loads along t.
__global__ __launch_bounds__(256)
void k_maskred(const float* __restrict__ ms, const float* __restrict__ mn,
               float* __restrict__ mrs, float* __restrict__ mrn) {
  __shared__ float ts[64][65];   // 65 pad: both phases <=2-way bank aliasing (free)
  __shared__ float tn[64][65];
  const int ft = blockIdx.x, tt = blockIdx.y, b = blockIdx.z;
  const int f0 = ft * 64, t0 = tt * 64;
  const int tq = threadIdx.x & 15;   // t-quad: 16 quads = 64 t
  const int fy = threadIdx.x >> 4;   // 0..15
  const int t = t0 + tq * 4;
  const bool tvalid = (t < NT);      // NT%4==0 so t<NT implies whole quad valid

#pragma unroll
  for (int p = 0; p < 4; p++) {
    const int fl = p * 16 + fy;
    const int f = f0 + fl;
    float4 as = make_float4(0.f, 0.f, 0.f, 0.f);
    float4 an = make_float4(0.f, 0.f, 0.f, 0.f);
    if (f < NF && tvalid) {
      const float* mbs = ms + (((size_t)b * NF + f) * NC) * NT + t;
      const float* mbn = mn + (((size_t)b * NF + f) * NC) * NT + t;
#pragma unroll
      for (int c = 0; c < NC; c++) {
        const float4 a = *(const float4*)(mbs + c * NT);
        as.x += fmaxf(a.x, 1e-6f); as.y += fmaxf(a.y, 1e-6f);
        as.z += fmaxf(a.z, 1e-6f); as.w += fmaxf(a.w, 1e-6f);
        const float4 q = *(const float4*)(mbn + c * NT);
        an.x += fmaxf(q.x, 1e-6f); an.y += fmaxf(q.y, 1e-6f);
        an.z += fmaxf(q.z, 1e-6f); an.w += fmaxf(q.w, 1e-6f);
      }
    }
    ts[fl][tq * 4 + 0] = as.x * 0.125f; ts[fl][tq * 4 + 1] = as.y * 0.125f;
    ts[fl][tq * 4 + 2] = as.z * 0.125f; ts[fl][tq * 4 + 3] = as.w * 0.125f;
    tn[fl][tq * 4 + 0] = an.x * 0.125f; tn[fl][tq * 4 + 1] = an.y * 0.125f;
    tn[fl][tq * 4 + 2] = an.z * 0.125f; tn[fl][tq * 4 + 3] = an.w * 0.125f;
  }
  __syncthreads();
  const int tx = threadIdx.x & 63, wy = threadIdx.x >> 6;
  for (int tl = wy; tl < 64; tl += 4) {
    const int tg = t0 + tl, f = f0 + tx;
    if (tg < NT && f < NF) {
      mrs[((size_t)b * NT + tg) * NF + f] = ts[tx][tl];
      mrn[((size_t)b * NT + tg) * NF + f] = tn[tx][tl];
    }
  }
}

// ---------------------------------------------------------------------------
__device__ __forceinline__ void accum_psd(const float* __restrict__ drb,
                                          const float* __restrict__ dib, int t,
                                          float m_s, float m_n,
                                          float* __restrict__ sr, float* __restrict__ si,
                                          float* __restrict__ nr, float* __restrict__ ni) {
  float xr[NC], xi[NC];
#pragma unroll
  for (int c = 0; c < NC; c++) {
    xr[c] = drb[(t * NC + c) * NF];
    xi[c] = dib[(t * NC + c) * NF];
  }
  int p = 0;
#pragma unroll
  for (int c = 0; c < NC; c++) {
#pragma unroll
    for (int e = c; e < NC; e++) {
      float pr = xr[c] * xr[e] + xi[c] * xi[e];
      float pi = xi[c] * xr[e] - xr[c] * xi[e];
      sr[p] += m_s * pr; si[p] += m_s * pi;
      nr[p] += m_n * pr; ni[p] += m_n * pi;
      p++;
    }
  }
}

__global__ __launch_bounds__(64, 2)
void k_psd(const float* __restrict__ dr, const float* __restrict__ di,
           const float* __restrict__ mrs, const float* __restrict__ mrn,
           float* __restrict__ comp) {
  const int fl = threadIdx.x;
  const int ft = blockIdx.x, b = blockIdx.y, tc = blockIdx.z;
  const int f = ft * 64 + fl;

  float sr[NPAIR], si[NPAIR], nr[NPAIR], ni[NPAIR];
#pragma unroll
  for (int p = 0; p < NPAIR; p++) { sr[p] = 0.f; si[p] = 0.f; nr[p] = 0.f; ni[p] = 0.f; }
  float Ss = 0.f, Sn = 0.f;

  if (f < NF) {
    const float* drb  = dr  + (size_t)b * NT * NC * NF + f;
    const float* dib  = di  + (size_t)b * NT * NC * NF + f;
    const float* mrsb = mrs + (size_t)b * NT * NF + f;
    const float* mrnb = mrn + (size_t)b * NT * NF + f;
    const int t0 = tc * TCHUNK;
    for (int tb = 0; tb < TCHUNK; tb += 2) {
      const int t = t0 + tb;
      const float ms0 = mrsb[(size_t)t * NF];
      const float ms1 = mrsb[(size_t)(t + 1) * NF];
      const float mn0 = mrnb[(size_t)t * NF];
      const float mn1 = mrnb[(size_t)(t + 1) * NF];
      Ss += ms0 + ms1; Sn += mn0 + mn1;
      accum_psd(drb, dib, t,     ms0, mn0, sr, si, nr, ni);
      accum_psd(drb, dib, t + 1, ms1, mn1, sr, si, nr, ni);
    }
  }

  float* out = comp + (((size_t)b * NFT + ft) * NE) * 64 + fl;
  if (f < NF) {
#pragma unroll
    for (int p = 0; p < NPAIR; p++) {
      unsafeAtomicAdd(&out[(2 * p) * 64], sr[p]);
      unsafeAtomicAdd(&out[(2 * p + 1) * 64], si[p]);
    }
#pragma unroll
    for (int p = 0; p < NPAIR; p++) {
      unsafeAtomicAdd(&out[(72 + 2 * p) * 64], nr[p]);
      unsafeAtomicAdd(&out[(72 + 2 * p + 1) * 64], ni[p]);
    }
    unsafeAtomicAdd(&out[144 * 64], Ss);
    unsafeAtomicAdd(&out[145 * 64], Sn);
  }
}

// ---------------------------------------------------------------------------
__global__ __launch_bounds__(320)
void k_attention(const float* __restrict__ comp,
                 const float* __restrict__ mlp_w, const float* __restrict__ mlp_b,
                 const float* __restrict__ gvec_w, const float* __restrict__ gvec_b,
                 float* __restrict__ e_buf) {
  __shared__ float feat[NF];
  __shared__ float wred[5];
  const int b = blockIdx.x >> 3, c = blockIdx.x & 7;
  const int tid = threadIdx.x;

  for (int f = tid; f < NF; f += 320) {
    const int ft = f >> 6, fl = f & 63;
    const float* base = comp + (((size_t)b * NFT + ft) * NE) * 64 + fl;
    float rs = 0.f, is = 0.f;
#pragma unroll
    for (int e = 0; e < NC; ++e) {
      if (e == c) continue;
      const int lo = (e < c) ? e : c, hi = (e < c) ? c : e;
      const int p = lo * 8 - (lo * (lo + 1)) / 2 + hi;
      rs += base[(2 * p) * 64];
      const float im = base[(2 * p + 1) * 64];
      is += (e > c) ? im : -im;   // row c: e<c needs conj
    }
    const float S = base[144 * 64];
    feat[f] = sqrtf(rs * rs + is * is) / (7.f * (S + 1e-15f));
  }
  __syncthreads();

  const int a = tid;  // blockDim == 320 == A
  float acc = mlp_b[a];
  for (int f = 0; f < NF; ++f) acc = fmaf(feat[f], mlp_w[f * 320 + a], acc);
  float contrib = tanhf(acc) * gvec_w[a];
#pragma unroll
  for (int off = 32; off > 0; off >>= 1) contrib += __shfl_down(contrib, off);
  if ((tid & 63) == 0) wred[tid >> 6] = contrib;
  __syncthreads();
  if (tid == 0) {
    float s = gvec_b[0];
#pragma unroll
    for (int w = 0; w < 5; ++w) s += wred[w];
    e_buf[blockIdx.x] = s;
  }
}

// ---------------------------------------------------------------------------
// Thread per (b,f,c): duplicated 8x8 complex Cholesky of psd_n per 8-lane
// group, one RHS column solve per thread, softmax(u) in-register,
// trace + u-weighted combine via shfl_xor butterflies over the 8-lane group.
__global__ __launch_bounds__(64)
void k_solve(const float* __restrict__ comp, const float* __restrict__ e_buf,
             float* __restrict__ wsvec) {
  const int lane = threadIdx.x;
  const int c = lane & 7, fsub = lane >> 3;
  const int b = blockIdx.y;
  const int f = blockIdx.x * 8 + fsub;
  if (f >= NF) return;
  const int ft = f >> 6, fl = f & 63;
  const float* base = comp + (((size_t)b * NFT + ft) * NE) * 64 + fl;

  float Ar[8][8], Ai[8][8];
#pragma unroll
  for (int j = 0; j < 8; j++) {
#pragma unroll
    for (int i = j; i < 8; i++) {
      const int p = j * 8 - (j * (j + 1)) / 2 + i;
      Ar[i][j] = base[(72 + 2 * p) * 64];
      Ai[i][j] = (i == j) ? 0.f : -base[(72 + 2 * p + 1) * 64];
    }
  }
#pragma unroll
  for (int i = 0; i < 8; i++) Ar[i][i] += 1e-15f;

  float dinv[8];
#pragma unroll
  for (int k = 0; k < 8; k++) {
    const float d = sqrtf(fmaxf(Ar[k][k], 1e-30f));
    const float id = 1.f / d;
    dinv[k] = id;
#pragma unroll
    for (int i = k + 1; i < 8; i++) { Ar[i][k] *= id; Ai[i][k] *= id; }
#pragma unroll
    for (int j = k + 1; j < 8; j++) {
#pragma unroll
      for (int i = j; i < 8; i++) {
        Ar[i][j] -= Ar[i][k] * Ar[j][k] + Ai[i][k] * Ai[j][k];
        Ai[i][j] -= Ai[i][k] * Ar[j][k] - Ar[i][k] * Ai[j][k];
      }
    }
  }

  // column c of psd_s: s[e] = psd_s[e][c]
  float syr[8], syi[8];
#pragma unroll
  for (int e = 0; e < 8; e++) {
    const int lo = (e < c) ? e : c, hi = (e < c) ? c : e;
    const int p = lo * 8 - (lo * (lo + 1)) / 2 + hi;
    syr[e] = base[(2 * p) * 64];
    const float im = base[(2 * p + 1) * 64];
    syi[e] = (e <= c) ? im : -im;
  }
  float yr[8], yi[8];
#pragma unroll
  for (int i = 0; i < 8; i++) {
    float ar = syr[i], ai = syi[i];
#pragma unroll
    for (int m = 0; m < 8; m++) {
      if (m < i) {
        ar -= Ar[i][m] * yr[m] - Ai[i][m] * yi[m];
        ai -= Ar[i][m] * yi[m] + Ai[i][m] * yr[m];
      }
    }
    yr[i] = ar * dinv[i]; yi[i] = ai * dinv[i];
  }
  float zr[8], zi[8];
#pragma unroll
  for (int i = 7; i >= 0; i--) {
    float ar = yr[i], ai = yi[i];
#pragma unroll
    for (int m = 0; m < 8; m++) {
      if (m > i) {
        ar -= Ar[m][i] * zr[m] + Ai[m][i] * zi[m];
        ai -= Ar[m][i] * zi[m] - Ai[m][i] * zr[m];
      }
    }
    zr[i] = ar * dinv[i]; zi[i] = ai * dinv[i];
  }

  // softmax(2*e) -> u[c]
  float ev[8], mx = -1e30f;
#pragma unroll
  for (int j = 0; j < 8; j++) { ev[j] = 2.f * e_buf[b * 8 + j]; mx = fmaxf(mx, ev[j]); }
  float ssum = 0.f;
#pragma unroll
  for (int j = 0; j < 8; j++) ssum += expf(ev[j] - mx);
  const float uc = expf(ev[c] - mx) / ssum;

  float trr = zr[c], tri = zi[c];
  float wr[8], wi[8];
#pragma unroll
  for (int e = 0; e < 8; e++) { wr[e] = zr[e] * uc; wi[e] = zi[e] * uc; }
#pragma unroll
  for (int m = 1; m <= 4; m <<= 1) {
    trr += __shfl_xor(trr, m); tri += __shfl_xor(tri, m);
#pragma unroll
    for (int e = 0; e < 8; e++) {
      wr[e] += __shfl_xor(wr[e], m);
      wi[e] += __shfl_xor(wi[e], m);
    }
  }

  const float denr = trr + 1e-15f, deni = tri;
  const float inv = 1.f / (denr * denr + deni * deni);
  float2* wv = (float2*)wsvec + ((size_t)b * NF + f) * 8;
  wv[c] = make_float2((wr[c] * denr + wi[c] * deni) * inv,
                      (wi[c] * denr - wr[c] * deni) * inv);
}

// ---------------------------------------------------------------------------
__global__ __launch_bounds__(64)
void k_apply(const float* __restrict__ dr, const float* __restrict__ di,
             const float* __restrict__ wsvec, float* __restrict__ out) {
  const int ft = blockIdx.x, b = blockIdx.y, tt = blockIdx.z;
  const int f = ft * 64 + threadIdx.x;
  if (f >= NF) return;
  float wr[8], wi[8];
  const float2* wv = (const float2*)wsvec + ((size_t)b * NF + f) * 8;
#pragma unroll
  for (int c = 0; c < 8; c++) { float2 w = wv[c]; wr[c] = w.x; wi[c] = w.y; }
  const float* drb = dr + (size_t)b * NT * NC * NF + f;
  const float* dib = di + (size_t)b * NT * NC * NF + f;
  float2* ob = (float2*)out + (size_t)b * NT * NF + f;
  const int t1 = tt * 16 + 16;
  for (int t = tt * 16; t < t1; ++t) {
    float re = 0.f, im = 0.f;
#pragma unroll
    for (int c = 0; c < 8; c++) {
      const float xr = drb[(t * NC + c) * NF];
      const float xi = dib[(t * NC + c) * NF];
      re += wr[c] * xr + wi[c] * xi;   // conj(ws) * x
      im += wr[c] * xi - wi[c] * xr;
    }
    ob[(size_t)t * NF] = make_float2(re, im);
  }
}

extern "C" void kernel_launch(void* const* d_in, const int* in_sizes, int n_in,
                              void* d_out, int out_size, void* d_ws, size_t ws_size,
                              hipStream_t stream) {
  const float* dr     = (const float*)d_in[0];
  const float* di     = (const float*)d_in[1];
  const float* msk_s  = (const float*)d_in[2];
  const float* msk_n  = (const float*)d_in[3];
  const float* mlp_w  = (const float*)d_in[4];
  const float* mlp_b  = (const float*)d_in[5];
  const float* gvec_w = (const float*)d_in[6];
  const float* gvec_b = (const float*)d_in[7];

  float* mrs   = (float*)d_ws;                                   // 3,283,200 floats
  float* mrn   = mrs + (size_t)NB * NT * NF;                     // 3,283,200
  float* comp  = mrn + (size_t)NB * NT * NF;                     // 672,768
  float* e_buf = comp + (size_t)NB * NFT * NE * 64;              // 64
  float* wsvec = e_buf + 64;                                     // 65,664
  float* out   = (float*)d_out;

  hipMemsetAsync(comp, 0, (size_t)NB * NFT * NE * 64 * sizeof(float), stream);
  k_maskred<<<dim3(NFT, 13, NB), 256, 0, stream>>>(msk_s, msk_n, mrs, mrn);
  k_psd<<<dim3(NFT, NB, NTC), 64, 0, stream>>>(dr, di, mrs, mrn, comp);
  k_attention<<<64, 320, 0, stream>>>(comp, mlp_w, mlp_b, gvec_w, gvec_b, e_buf);
  k_solve<<<dim3(65, NB), 64, 0, stream>>>(comp, e_buf, wsvec);
  k_apply<<<dim3(NFT, NB, 50), 64, 0, stream>>>(dr, di, wsvec, out);
}